// Round 22
// baseline (322.444 us; speedup 1.0000x reference)
//
#include <hip/hip_runtime.h>
#include <hip/hip_bf16.h>
#include <float.h>

#define IN_DIM 128
#define EDGE_DIM 32
#define HID 64
#define BKT_G 64          // nodes per bucket
#define BCAP 3072         // per-bucket capacity
#define NBKT_MAX 784
#define CHUNK 4096        // edges per binning block
#define ENC_NEG_INF 0x007FFFFFu

// Monotone float<->uint encoding: unsigned compare == float compare
__device__ __forceinline__ unsigned encf(float f) {
    unsigned u = __float_as_uint(f);
    return (u & 0x80000000u) ? ~u : (u | 0x80000000u);
}
__device__ __forceinline__ float dec0(unsigned u) {   // empty segment -> 0
    if (u == ENC_NEG_INF) return 0.0f;
    return (u & 0x80000000u) ? __uint_as_float(u ^ 0x80000000u) : __uint_as_float(~u);
}

// ---------------- K1: u,v,w projections + stride detect + workspace zeroing ----------------
__global__ void k_uvw(const float* __restrict__ Wsrc, const float* __restrict__ Wdst,
                      const float* __restrict__ Wedge, const float* __restrict__ avec,
                      const int* __restrict__ ei32, int* sflag,
                      float* u, float* v, float* w,
                      int* gcur, float* stats, int nbkt) {
    int gt = blockIdx.x * blockDim.x + threadIdx.x;
    int gstride = gridDim.x * blockDim.x;
    for (int i = gt; i < 2 * nbkt; i += gstride) gcur[i] = 0;
    for (int i = gt; i < 512; i += gstride) stats[i] = 0.0f;
    if (gt == 0) {
        int odd_or = ei32[1] | ei32[3] | ei32[5] | ei32[7] | ei32[9] | ei32[11];
        sflag[0] = (odd_or == 0) ? 2 : 1;   // int64 -> 2 words/elem, int32 -> 1
    }
    int wave = gt >> 6;
    int lane = threadIdx.x & 63;
    const float* src; float* dst; int row;
    if (wave < 128)      { src = Wsrc;  dst = u; row = wave; }
    else if (wave < 256) { src = Wdst;  dst = v; row = wave - 128; }
    else if (wave < 288) { src = Wedge; dst = w; row = wave - 256; }
    else return;
    float acc = src[row * HID + lane] * avec[lane];
    for (int o = 32; o >= 1; o >>= 1) acc += __shfl_xor(acc, o);
    if (lane == 0) dst[row] = acc;
}

// ---------------- K2: merged p/q projection + edge-attr dot ----------------
__global__ void k_pqdot(const float* __restrict__ x, const float* __restrict__ u,
                        const float* __restrict__ v,
                        const float* __restrict__ ea, const float* __restrict__ w,
                        float* p, float* q, float* rdot, int N, int E, int pqBlocks) {
    if ((int)blockIdx.x < pqBlocks) {
        int wave = (blockIdx.x * blockDim.x + threadIdx.x) >> 6;
        int lane = threadIdx.x & 63;
        if (wave >= N) return;
        const float* xr = x + (size_t)wave * IN_DIM;
        float a0 = xr[lane], a1 = xr[lane + 64];
        float pp = a0 * u[lane] + a1 * u[lane + 64];
        float qq = a0 * v[lane] + a1 * v[lane + 64];
        for (int m = 32; m >= 1; m >>= 1) { pp += __shfl_xor(pp, m); qq += __shfl_xor(qq, m); }
        if (lane == 0) { p[wave] = pp; q[wave] = qq; }
    } else {
        int gid = (blockIdx.x - pqBlocks) * blockDim.x + threadIdx.x;
        int e = gid >> 3;
        int j = gid & 7;
        if (e >= E) return;
        float4 av = ((const float4*)ea)[(size_t)e * 8 + j];
        float4 wv = ((const float4*)w)[j];
        float val = av.x * wv.x + av.y * wv.y + av.z * wv.z + av.w * wv.w;
        val += __shfl_xor(val, 4);
        val += __shfl_xor(val, 2);
        val += __shfl_xor(val, 1);
        if (j == 0) rdot[e] = val;
    }
}

// ---------------- K3: score + block-local two-phase binning ----------------
__global__ __launch_bounds__(256) void k_binscore(const int* __restrict__ ei,
                                                  const int* __restrict__ sflag,
                                                  const float* __restrict__ rdot,
                                                  const float* __restrict__ p,
                                                  const float* __restrict__ q,
                                                  float* scores,
                                                  int* gcur_col, int* gcur_row,
                                                  unsigned* bbuf_col, unsigned* bbuf_row,
                                                  int E, int nbkt) {
    __shared__ int lc[NBKT_MAX], lrw[NBKT_MAX];
    __shared__ int gc[NBKT_MAX], grw[NBKT_MAX];
    int tid = threadIdx.x;
    int e0 = blockIdx.x * CHUNK;
    int e1 = e0 + CHUNK; if (e1 > E) e1 = E;
    for (int i = tid; i < nbkt; i += 256) { lc[i] = 0; lrw[i] = 0; }
    __syncthreads();
    int st = sflag[0];
    for (int e = e0 + tid; e < e1; e += 256) {
        int r = ei[(size_t)st * e];
        int c = ei[(size_t)st * (E + e)];
        float sc = rdot[e] + p[r] + q[c];
        scores[e] = (sc > 0.f) ? sc : 0.2f * sc;
        atomicAdd(&lc[c >> 6], 1);
        atomicAdd(&lrw[r >> 6], 1);
    }
    __syncthreads();
    for (int b = tid; b < nbkt; b += 256) {
        int n1 = lc[b];  if (n1) gc[b]  = atomicAdd(&gcur_col[b], n1);
        int n2 = lrw[b]; if (n2) grw[b] = atomicAdd(&gcur_row[b], n2);
        lc[b] = 0; lrw[b] = 0;
    }
    __syncthreads();
    for (int e = e0 + tid; e < e1; e += 256) {
        int r = ei[(size_t)st * e];
        int c = ei[(size_t)st * (E + e)];
        int pos = gc[c >> 6] + atomicAdd(&lc[c >> 6], 1);
        if (pos < BCAP) bbuf_col[(size_t)(c >> 6) * BCAP + pos] = (unsigned)((e << 6) | (c & 63));
        int pos2 = grw[r >> 6] + atomicAdd(&lrw[r >> 6], 1);
        if (pos2 < BCAP) bbuf_row[(size_t)(r >> 6) * BCAP + pos2] = (unsigned)((e << 6) | (r & 63));
    }
}

// ---------------- K4: col-bucket softmax + attn + flat-parallel fwd max ----------------
__global__ __launch_bounds__(512) void k_sortfwd(float* scores, const float* __restrict__ msg,
                                                 const int* __restrict__ bcur,
                                                 const unsigned* __restrict__ bbuf,
                                                 float* fwd, int N) {
    __shared__ unsigned raw[BCAP];
    __shared__ unsigned srt[BCAP];
    __shared__ float    ssc[BCAP];
    __shared__ unsigned facc[BKT_G * HID];   // 16 KB accumulator
    __shared__ int cnt[BKT_G], cur[BKT_G], sstart[BKT_G + 1];
    int b = blockIdx.x, tid = threadIdx.x;
    int M = bcur[b]; if (M > BCAP) M = BCAP;
    if (tid < BKT_G) cnt[tid] = 0;
    __syncthreads();
    for (int i = tid; i < M; i += 512) {       // load + histogram
        unsigned v = bbuf[(size_t)b * BCAP + i];
        raw[i] = v;
        atomicAdd(&cnt[v & 63], 1);
    }
    for (int i = tid; i < BKT_G * HID; i += 512) facc[i] = ENC_NEG_INF;
    __syncthreads();
    if (tid < BKT_G) {                         // wave 0: exclusive scan
        int val = cnt[tid];
        int inc = val;
        for (int off = 1; off < BKT_G; off <<= 1) {
            int o = __shfl_up(inc, off);
            if (tid >= off) inc += o;
        }
        sstart[tid + 1] = inc;
        if (tid == 0) sstart[0] = 0;
        cur[tid] = inc - val;
    }
    __syncthreads();
    for (int j = tid; j < M; j += 512) {       // scatter into node-sorted order
        unsigned v = raw[j];
        int posn = atomicAdd(&cur[v & 63], 1);
        srt[posn] = v;
    }
    __syncthreads();
    for (int i = tid; i < M; i += 512) ssc[i] = scores[srt[i] >> 6];
    __syncthreads();
    int wave = tid >> 6, lane = tid & 63;
    // per-node softmax (LDS-only, cheap) + attn writeback
    for (int n = wave; n < BKT_G; n += 8) {
        int a0 = sstart[n], len = sstart[n + 1] - a0;
        if (len == 0) continue;
        float m = -FLT_MAX;
        for (int k = lane; k < len; k += 64) m = fmaxf(m, ssc[a0 + k]);
        for (int o = 32; o >= 1; o >>= 1) m = fmaxf(m, __shfl_xor(m, o));
        float ssum = 0.f;
        for (int k = lane; k < len; k += 64) ssum += expf(ssc[a0 + k] - m);
        for (int o = 32; o >= 1; o >>= 1) ssum += __shfl_xor(ssum, o);
        float rcp = 1.f / ssum;
        for (int k = lane; k < len; k += 64) {
            int i = a0 + k;
            float at = expf(ssc[i] - m) * rcp;
            ssc[i] = at;
            scores[srt[i] >> 6] = at;
        }
    }
    __syncthreads();
    // flat edge-parallel gather: independent iterations, 4 loads in flight
    int i = wave;
    for (; i + 24 < M; i += 32) {
        unsigned s0 = srt[i], s1 = srt[i + 8], s2 = srt[i + 16], s3 = srt[i + 24];
        float a0 = ssc[i], a1 = ssc[i + 8], a2 = ssc[i + 16], a3 = ssc[i + 24];
        float v0 = msg[(size_t)(s0 >> 6) * HID + lane] * a0;
        float v1 = msg[(size_t)(s1 >> 6) * HID + lane] * a1;
        float v2 = msg[(size_t)(s2 >> 6) * HID + lane] * a2;
        float v3 = msg[(size_t)(s3 >> 6) * HID + lane] * a3;
        atomicMax(&facc[(s0 & 63) * HID + lane], encf(v0));
        atomicMax(&facc[(s1 & 63) * HID + lane], encf(v1));
        atomicMax(&facc[(s2 & 63) * HID + lane], encf(v2));
        atomicMax(&facc[(s3 & 63) * HID + lane], encf(v3));
    }
    for (; i < M; i += 8) {
        unsigned s0 = srt[i];
        float v0 = msg[(size_t)(s0 >> 6) * HID + lane] * ssc[i];
        atomicMax(&facc[(s0 & 63) * HID + lane], encf(v0));
    }
    __syncthreads();
    // writeout (empties -> 0 via dec0)
    for (int idx = tid; idx < BKT_G * HID; idx += 512) {
        int node = b * BKT_G + (idx >> 6);
        if (node < N) fwd[(size_t)node * HID + (idx & 63)] = dec0(facc[idx]);
    }
}

// ---------------- K5: row-bucket flat-parallel bwd max (no sort needed) ----------------
__global__ __launch_bounds__(512) void k_sortbwd(const float* __restrict__ scores,
                                                 const float* __restrict__ msg,
                                                 const int* __restrict__ bcur,
                                                 const unsigned* __restrict__ bbuf,
                                                 float* bwd, int N) {
    __shared__ unsigned raw[BCAP];
    __shared__ float    ssc[BCAP];
    __shared__ unsigned facc[BKT_G * HID];   // 16 KB
    int b = blockIdx.x, tid = threadIdx.x;
    int M = bcur[b]; if (M > BCAP) M = BCAP;
    for (int i = tid; i < M; i += 512) raw[i] = bbuf[(size_t)b * BCAP + i];
    for (int i = tid; i < BKT_G * HID; i += 512) facc[i] = ENC_NEG_INF;
    __syncthreads();
    for (int i = tid; i < M; i += 512) ssc[i] = scores[raw[i] >> 6];   // attn
    __syncthreads();
    int wave = tid >> 6, lane = tid & 63;
    int i = wave;
    for (; i + 24 < M; i += 32) {
        unsigned s0 = raw[i], s1 = raw[i + 8], s2 = raw[i + 16], s3 = raw[i + 24];
        float a0 = ssc[i], a1 = ssc[i + 8], a2 = ssc[i + 16], a3 = ssc[i + 24];
        float v0 = msg[(size_t)(s0 >> 6) * HID + lane] * a0;
        float v1 = msg[(size_t)(s1 >> 6) * HID + lane] * a1;
        float v2 = msg[(size_t)(s2 >> 6) * HID + lane] * a2;
        float v3 = msg[(size_t)(s3 >> 6) * HID + lane] * a3;
        atomicMax(&facc[(s0 & 63) * HID + lane], encf(v0));
        atomicMax(&facc[(s1 & 63) * HID + lane], encf(v1));
        atomicMax(&facc[(s2 & 63) * HID + lane], encf(v2));
        atomicMax(&facc[(s3 & 63) * HID + lane], encf(v3));
    }
    for (; i < M; i += 8) {
        unsigned s0 = raw[i];
        float v0 = msg[(size_t)(s0 >> 6) * HID + lane] * ssc[i];
        atomicMax(&facc[(s0 & 63) * HID + lane], encf(v0));
    }
    __syncthreads();
    for (int idx = tid; idx < BKT_G * HID; idx += 512) {
        int node = b * BKT_G + (idx >> 6);
        if (node < N) bwd[(size_t)node * HID + (idx & 63)] = dec0(facc[idx]);
    }
}

// ---------------- K6: pre1 = [fwd,bwd]@W1 + b1, 4-chain ILP, fused BN stats ----------------
__global__ __launch_bounds__(256) void k_mlp1(const float* __restrict__ fwd,
                                              const float* __restrict__ bwd,
                                              const float* __restrict__ W1,
                                              const float* __restrict__ b1,
                                              float* pre1, float* gsum, float* gss, int N) {
    __shared__ float lsum[HID], lss[HID];
    int t = threadIdx.x;
    if (t < HID) { lsum[t] = 0.f; lss[t] = 0.f; }
    __syncthreads();
    int h = t & 63, lr = t >> 6;
    float bh = b1[h];
    float s = 0.f, ssq = 0.f;
    for (int n = blockIdx.x * 4 + lr; n < N; n += gridDim.x * 4) {
        const float* fr = fwd + (size_t)n * HID;
        const float* br = bwd + (size_t)n * HID;
        float a0 = bh, a1 = 0.f, a2 = 0.f, a3 = 0.f;
#pragma unroll
        for (int k = 0; k < HID; k += 4) {
            a0 += fr[k]     * W1[k * HID + h];
            a1 += fr[k + 1] * W1[(k + 1) * HID + h];
            a2 += fr[k + 2] * W1[(k + 2) * HID + h];
            a3 += fr[k + 3] * W1[(k + 3) * HID + h];
        }
#pragma unroll
        for (int k = 0; k < HID; k += 4) {
            a0 += br[k]     * W1[(HID + k) * HID + h];
            a1 += br[k + 1] * W1[(HID + k + 1) * HID + h];
            a2 += br[k + 2] * W1[(HID + k + 2) * HID + h];
            a3 += br[k + 3] * W1[(HID + k + 3) * HID + h];
        }
        float acc = (a0 + a1) + (a2 + a3);
        pre1[(size_t)n * HID + h] = acc;
        s += acc; ssq += acc * acc;
    }
    atomicAdd(&lsum[h], s);
    atomicAdd(&lss[h], ssq);
    __syncthreads();
    if (t < HID) { atomicAdd(&gsum[t], lsum[t]); atomicAdd(&gss[t], lss[t]); }
}

// ---------------- K7: pre2 = relu(bn1(pre1))@W2 + b2; bnfin1 folded; 4-chain ILP ----------------
__global__ __launch_bounds__(256) void k_mlp2(const float* __restrict__ pre1,
                                              const float* __restrict__ gsum1,
                                              const float* __restrict__ gss1,
                                              const float* __restrict__ g1,
                                              const float* __restrict__ bb1,
                                              const float* __restrict__ W2,
                                              const float* __restrict__ b2v,
                                              float* pre2, float* gsum, float* gss, int N) {
    __shared__ float lsum[HID], lss[HID];
    __shared__ float sc1[HID], sh1[HID];
    int t = threadIdx.x;
    if (t < HID) {
        lsum[t] = 0.f; lss[t] = 0.f;
        float invN = 1.0f / (float)N;
        float mu = gsum1[t] * invN;
        float var = gss1[t] * invN - mu * mu;
        float rs = rsqrtf(var + 1e-5f);
        float s1 = rs * g1[t];
        sc1[t] = s1;
        sh1[t] = bb1[t] - mu * s1;
    }
    __syncthreads();
    int h = t & 63, lr = t >> 6;
    float bh = b2v[h];
    float s = 0.f, ssq = 0.f;
    for (int n = blockIdx.x * 4 + lr; n < N; n += gridDim.x * 4) {
        const float* pr = pre1 + (size_t)n * HID;
        float a0 = bh, a1 = 0.f, a2 = 0.f, a3 = 0.f;
#pragma unroll
        for (int k = 0; k < HID; k += 4) {
            float z0 = pr[k]     * sc1[k]     + sh1[k];     z0 = (z0 > 0.f) ? z0 : 0.f;
            float z1 = pr[k + 1] * sc1[k + 1] + sh1[k + 1]; z1 = (z1 > 0.f) ? z1 : 0.f;
            float z2 = pr[k + 2] * sc1[k + 2] + sh1[k + 2]; z2 = (z2 > 0.f) ? z2 : 0.f;
            float z3 = pr[k + 3] * sc1[k + 3] + sh1[k + 3]; z3 = (z3 > 0.f) ? z3 : 0.f;
            a0 += z0 * W2[k * HID + h];
            a1 += z1 * W2[(k + 1) * HID + h];
            a2 += z2 * W2[(k + 2) * HID + h];
            a3 += z3 * W2[(k + 3) * HID + h];
        }
        float acc = (a0 + a1) + (a2 + a3);
        pre2[(size_t)n * HID + h] = acc;
        s += acc; ssq += acc * acc;
    }
    atomicAdd(&lsum[h], s);
    atomicAdd(&lss[h], ssq);
    __syncthreads();
    if (t < HID) { atomicAdd(&gsum[t], lsum[t]); atomicAdd(&gss[t], lss[t]); }
}

// ---------------- K8: bnfin2 folded; h2 = relu(bn2(pre2)); gate; f32 out ----------------
__global__ __launch_bounds__(256) void k_out(const float* __restrict__ pre2,
                                             const float* __restrict__ gsum2,
                                             const float* __restrict__ gss2,
                                             const float* __restrict__ g2,
                                             const float* __restrict__ bb2,
                                             const float* __restrict__ amw,
                                             const float* __restrict__ amb,
                                             float* out, int N) {
    __shared__ float sc2[HID], sh2[HID];
    int t = threadIdx.x;
    if (t < HID) {
        float invN = 1.0f / (float)N;
        float mu = gsum2[t] * invN;
        float var = gss2[t] * invN - mu * mu;
        float rs = rsqrtf(var + 1e-5f);
        float s2 = rs * g2[t];
        sc2[t] = s2;
        sh2[t] = bb2[t] - mu * s2;
    }
    __syncthreads();
    int gid = blockIdx.x * blockDim.x + t;
    int n = gid >> 6, h = gid & 63;
    if (n >= N) return;
    float z = pre2[(size_t)n * HID + h] * sc2[h] + sh2[h];
    float h2 = (z > 0.f) ? z : 0.f;
    out[(size_t)n * HID + h] = h2;
    float part = h2 * amw[h];
    for (int m = 32; m >= 1; m >>= 1) part += __shfl_xor(part, m);
    if (h == 0) {
        float gate = 1.0f / (1.0f + expf(-(part + amb[0])));
        out[(size_t)N * HID + n] = gate;
    }
}

extern "C" void kernel_launch(void* const* d_in, const int* in_sizes, int n_in,
                              void* d_out, int out_size, void* d_ws, size_t ws_size,
                              hipStream_t stream) {
    const float* x     = (const float*)d_in[0];
    const int*   ei    = (const int*)d_in[1];
    const float* ea    = (const float*)d_in[2];
    const float* msg   = (const float*)d_in[3];
    const float* Wsrc  = (const float*)d_in[4];
    const float* Wdst  = (const float*)d_in[5];
    const float* Wedge = (const float*)d_in[6];
    const float* avec  = (const float*)d_in[7];
    const float* W1    = (const float*)d_in[8];
    const float* b1    = (const float*)d_in[9];
    const float* g1    = (const float*)d_in[10];
    const float* bb1   = (const float*)d_in[11];
    const float* W2    = (const float*)d_in[12];
    const float* b2    = (const float*)d_in[13];
    const float* g2    = (const float*)d_in[14];
    const float* bb2   = (const float*)d_in[15];
    const float* amw   = (const float*)d_in[16];
    const float* amb   = (const float*)d_in[17];
    float* out = (float*)d_out;

    const int N = in_sizes[0] / IN_DIM;   // 50000
    const int E = in_sizes[1] / 2;        // 800000
    const int NH = N * HID;
    const int nbkt = (N + BKT_G - 1) / BKT_G;   // 782

    // ---- workspace ----
    float* ws = (float*)d_ws;
    float* gsum1  = ws;
    float* gss1   = ws + 64;
    float* gsum2  = ws + 128;
    float* gss2   = ws + 192;
    int*   sflag  = (int*)(ws + 512);
    float* u      = ws + 576;
    float* v      = ws + 704;
    float* w      = ws + 832;   // 16B-aligned
    float* T        = ws + 1024;
    float* p        = T;                               // N
    float* q        = p + N;                           // N
    float* scores   = q + N;                           // E (attn after sortfwd)
    float* rdot     = scores + E;                      // E
    int*   gcur_col = (int*)(rdot + E);                // nbkt
    int*   gcur_row = gcur_col + nbkt;                 // nbkt
    unsigned* bbuf_col = (unsigned*)(gcur_row + nbkt);          // nbkt*BCAP
    unsigned* bbuf_row = bbuf_col + (size_t)nbkt * BCAP;        // nbkt*BCAP
    size_t T_words  = 2 * (size_t)N + 2 * (size_t)E + 2 * (size_t)nbkt
                    + 2 * (size_t)nbkt * BCAP;
    size_t T_sz     = (T_words < (size_t)NH) ? (size_t)NH : T_words;
    float* fwd  = ws + 1024 + T_sz;                    // NH
    float* bwd  = fwd + (size_t)NH;                    // NH
    float* pre1 = T;                                   // overlay transients (dead)
    float* pre2 = fwd;                                 // overlay fwd (dead after mlp1)

    const int pqBlocks   = (N * 64 + 255) / 256;       // 12500
    const int edotBlocks = (E * 8 + 255) / 256;        // 25000

    hipLaunchKernelGGL(k_uvw, dim3(72), dim3(256), 0, stream,
                       Wsrc, Wdst, Wedge, avec, ei, sflag, u, v, w,
                       gcur_col, ws, nbkt);
    hipLaunchKernelGGL(k_pqdot, dim3(pqBlocks + edotBlocks), dim3(256), 0, stream,
                       x, u, v, ea, w, p, q, rdot, N, E, pqBlocks);
    hipLaunchKernelGGL(k_binscore, dim3((E + CHUNK - 1) / CHUNK), dim3(256), 0, stream,
                       ei, sflag, rdot, p, q, scores,
                       gcur_col, gcur_row, bbuf_col, bbuf_row, E, nbkt);
    hipLaunchKernelGGL(k_sortfwd, dim3(nbkt), dim3(512), 0, stream,
                       scores, msg, gcur_col, bbuf_col, fwd, N);
    hipLaunchKernelGGL(k_sortbwd, dim3(nbkt), dim3(512), 0, stream,
                       scores, msg, gcur_row, bbuf_row, bwd, N);
    hipLaunchKernelGGL(k_mlp1, dim3(1024), dim3(256), 0, stream,
                       fwd, bwd, W1, b1, pre1, gsum1, gss1, N);
    hipLaunchKernelGGL(k_mlp2, dim3(1024), dim3(256), 0, stream,
                       pre1, gsum1, gss1, g1, bb1, W2, b2, pre2, gsum2, gss2, N);
    hipLaunchKernelGGL(k_out, dim3(pqBlocks), dim3(256), 0, stream,
                       pre2, gsum2, gss2, g2, bb2, amw, amb, out, N);
}

// Round 23
// 307.632 us; speedup vs baseline: 1.0481x; 1.0481x over previous
//
#include <hip/hip_runtime.h>
#include <hip/hip_bf16.h>
#include <float.h>

#define IN_DIM 128
#define EDGE_DIM 32
#define HID 64
#define BKT_G 64          // nodes per bucket
#define BCAP 3072         // per-bucket capacity
#define NBKT_MAX 784
#define CHUNK 4096        // edges per binning block

// ---------------- K1: u,v,w projections + stride detect + workspace zeroing ----------------
__global__ void k_uvw(const float* __restrict__ Wsrc, const float* __restrict__ Wdst,
                      const float* __restrict__ Wedge, const float* __restrict__ avec,
                      const int* __restrict__ ei32, int* sflag,
                      float* u, float* v, float* w,
                      int* gcur, float* stats, int nbkt) {
    int gt = blockIdx.x * blockDim.x + threadIdx.x;
    int gstride = gridDim.x * blockDim.x;
    for (int i = gt; i < 2 * nbkt; i += gstride) gcur[i] = 0;
    for (int i = gt; i < 512; i += gstride) stats[i] = 0.0f;
    if (gt == 0) {
        int odd_or = ei32[1] | ei32[3] | ei32[5] | ei32[7] | ei32[9] | ei32[11];
        sflag[0] = (odd_or == 0) ? 2 : 1;   // int64 -> 2 words/elem, int32 -> 1
    }
    int wave = gt >> 6;
    int lane = threadIdx.x & 63;
    const float* src; float* dst; int row;
    if (wave < 128)      { src = Wsrc;  dst = u; row = wave; }
    else if (wave < 256) { src = Wdst;  dst = v; row = wave - 128; }
    else if (wave < 288) { src = Wedge; dst = w; row = wave - 256; }
    else return;
    float acc = src[row * HID + lane] * avec[lane];
    for (int o = 32; o >= 1; o >>= 1) acc += __shfl_xor(acc, o);
    if (lane == 0) dst[row] = acc;
}

// ---------------- K2: merged p/q projection + edge-attr dot ----------------
__global__ void k_pqdot(const float* __restrict__ x, const float* __restrict__ u,
                        const float* __restrict__ v,
                        const float* __restrict__ ea, const float* __restrict__ w,
                        float* p, float* q, float* rdot, int N, int E, int pqBlocks) {
    if ((int)blockIdx.x < pqBlocks) {
        int wave = (blockIdx.x * blockDim.x + threadIdx.x) >> 6;
        int lane = threadIdx.x & 63;
        if (wave >= N) return;
        const float* xr = x + (size_t)wave * IN_DIM;
        float a0 = xr[lane], a1 = xr[lane + 64];
        float pp = a0 * u[lane] + a1 * u[lane + 64];
        float qq = a0 * v[lane] + a1 * v[lane + 64];
        for (int m = 32; m >= 1; m >>= 1) { pp += __shfl_xor(pp, m); qq += __shfl_xor(qq, m); }
        if (lane == 0) { p[wave] = pp; q[wave] = qq; }
    } else {
        int gid = (blockIdx.x - pqBlocks) * blockDim.x + threadIdx.x;
        int e = gid >> 3;
        int j = gid & 7;
        if (e >= E) return;
        float4 av = ((const float4*)ea)[(size_t)e * 8 + j];
        float4 wv = ((const float4*)w)[j];
        float val = av.x * wv.x + av.y * wv.y + av.z * wv.z + av.w * wv.w;
        val += __shfl_xor(val, 4);
        val += __shfl_xor(val, 2);
        val += __shfl_xor(val, 1);
        if (j == 0) rdot[e] = val;
    }
}

// ---------------- K3: score + block-local two-phase binning ----------------
__global__ __launch_bounds__(256) void k_binscore(const int* __restrict__ ei,
                                                  const int* __restrict__ sflag,
                                                  const float* __restrict__ rdot,
                                                  const float* __restrict__ p,
                                                  const float* __restrict__ q,
                                                  float* scores,
                                                  int* gcur_col, int* gcur_row,
                                                  unsigned* bbuf_col, unsigned* bbuf_row,
                                                  int E, int nbkt) {
    __shared__ int lc[NBKT_MAX], lrw[NBKT_MAX];
    __shared__ int gc[NBKT_MAX], grw[NBKT_MAX];
    int tid = threadIdx.x;
    int e0 = blockIdx.x * CHUNK;
    int e1 = e0 + CHUNK; if (e1 > E) e1 = E;
    for (int i = tid; i < nbkt; i += 256) { lc[i] = 0; lrw[i] = 0; }
    __syncthreads();
    int st = sflag[0];
    for (int e = e0 + tid; e < e1; e += 256) {
        int r = ei[(size_t)st * e];
        int c = ei[(size_t)st * (E + e)];
        float sc = rdot[e] + p[r] + q[c];
        scores[e] = (sc > 0.f) ? sc : 0.2f * sc;
        atomicAdd(&lc[c >> 6], 1);
        atomicAdd(&lrw[r >> 6], 1);
    }
    __syncthreads();
    for (int b = tid; b < nbkt; b += 256) {
        int n1 = lc[b];  if (n1) gc[b]  = atomicAdd(&gcur_col[b], n1);
        int n2 = lrw[b]; if (n2) grw[b] = atomicAdd(&gcur_row[b], n2);
        lc[b] = 0; lrw[b] = 0;
    }
    __syncthreads();
    for (int e = e0 + tid; e < e1; e += 256) {
        int r = ei[(size_t)st * e];
        int c = ei[(size_t)st * (E + e)];
        int pos = gc[c >> 6] + atomicAdd(&lc[c >> 6], 1);
        if (pos < BCAP) bbuf_col[(size_t)(c >> 6) * BCAP + pos] = (unsigned)((e << 6) | (c & 63));
        int pos2 = grw[r >> 6] + atomicAdd(&lrw[r >> 6], 1);
        if (pos2 < BCAP) bbuf_row[(size_t)(r >> 6) * BCAP + pos2] = (unsigned)((e << 6) | (r & 63));
    }
}

// ---------------- K4: per-bucket sorted-LDS softmax + attn + fwd max ----------------
__global__ __launch_bounds__(512) void k_sortfwd(float* scores, const float* __restrict__ msg,
                                                 const int* __restrict__ bcur,
                                                 const unsigned* __restrict__ bbuf,
                                                 float* fwd, int N) {
    __shared__ unsigned raw[BCAP];
    __shared__ unsigned srt[BCAP];
    __shared__ float    ssc[BCAP];
    __shared__ int cnt[BKT_G], cur[BKT_G], sstart[BKT_G + 1];
    int b = blockIdx.x, tid = threadIdx.x;
    int M = bcur[b]; if (M > BCAP) M = BCAP;
    if (tid < BKT_G) cnt[tid] = 0;
    __syncthreads();
    for (int i = tid; i < M; i += 512) {       // load + histogram
        unsigned v = bbuf[(size_t)b * BCAP + i];
        raw[i] = v;
        atomicAdd(&cnt[v & 63], 1);
    }
    __syncthreads();
    if (tid < BKT_G) {                         // wave 0: exclusive scan
        int val = cnt[tid];
        int inc = val;
        for (int off = 1; off < BKT_G; off <<= 1) {
            int o = __shfl_up(inc, off);
            if (tid >= off) inc += o;
        }
        sstart[tid + 1] = inc;
        if (tid == 0) sstart[0] = 0;
        cur[tid] = inc - val;
    }
    __syncthreads();
    for (int j = tid; j < M; j += 512) {       // scatter into node-sorted order
        unsigned v = raw[j];
        int posn = atomicAdd(&cur[v & 63], 1);
        srt[posn] = v;
    }
    __syncthreads();
    for (int i = tid; i < M; i += 512) ssc[i] = scores[srt[i] >> 6];
    __syncthreads();
    int wave = tid >> 6, lane = tid & 63;
    for (int n = wave; n < BKT_G; n += 8) {
        int node = b * BKT_G + n;
        if (node >= N) continue;
        int a0 = sstart[n], len = sstart[n + 1] - a0;
        if (len == 0) { fwd[(size_t)node * HID + lane] = 0.f; continue; }
        float m = -FLT_MAX;
        for (int k = lane; k < len; k += 64) m = fmaxf(m, ssc[a0 + k]);
        for (int o = 32; o >= 1; o >>= 1) m = fmaxf(m, __shfl_xor(m, o));
        float ssum = 0.f;
        for (int k = lane; k < len; k += 64) ssum += expf(ssc[a0 + k] - m);
        for (int o = 32; o >= 1; o >>= 1) ssum += __shfl_xor(ssum, o);
        float rcp = 1.f / ssum;
        for (int k = lane; k < len; k += 64) {
            int i = a0 + k;
            float at = expf(ssc[i] - m) * rcp;
            ssc[i] = at;
            scores[srt[i] >> 6] = at;
        }
        asm volatile("s_waitcnt lgkmcnt(0)" ::: "memory");
        float acc = -FLT_MAX;
        int k = 0;
        for (; k + 8 <= len; k += 8) {
            float vv[8];
#pragma unroll
            for (int u8 = 0; u8 < 8; u8++) {
                int i = a0 + k + u8;
                vv[u8] = msg[(size_t)(srt[i] >> 6) * HID + lane] * ssc[i];
            }
#pragma unroll
            for (int u8 = 0; u8 < 8; u8++) acc = fmaxf(acc, vv[u8]);
        }
        for (; k < len; k++) {
            int i = a0 + k;
            acc = fmaxf(acc, msg[(size_t)(srt[i] >> 6) * HID + lane] * ssc[i]);
        }
        fwd[(size_t)node * HID + lane] = acc;
    }
}

// ---------------- K5: per-bucket sorted-LDS bwd max (attn precomputed) ----------------
__global__ __launch_bounds__(512) void k_sortbwd(const float* __restrict__ scores,
                                                 const float* __restrict__ msg,
                                                 const int* __restrict__ bcur,
                                                 const unsigned* __restrict__ bbuf,
                                                 float* bwd, int N) {
    __shared__ unsigned raw[BCAP];
    __shared__ unsigned srt[BCAP];
    __shared__ float    ssc[BCAP];
    __shared__ int cnt[BKT_G], cur[BKT_G], sstart[BKT_G + 1];
    int b = blockIdx.x, tid = threadIdx.x;
    int M = bcur[b]; if (M > BCAP) M = BCAP;
    if (tid < BKT_G) cnt[tid] = 0;
    __syncthreads();
    for (int i = tid; i < M; i += 512) {
        unsigned v = bbuf[(size_t)b * BCAP + i];
        raw[i] = v;
        atomicAdd(&cnt[v & 63], 1);
    }
    __syncthreads();
    if (tid < BKT_G) {
        int val = cnt[tid];
        int inc = val;
        for (int off = 1; off < BKT_G; off <<= 1) {
            int o = __shfl_up(inc, off);
            if (tid >= off) inc += o;
        }
        sstart[tid + 1] = inc;
        if (tid == 0) sstart[0] = 0;
        cur[tid] = inc - val;
    }
    __syncthreads();
    for (int j = tid; j < M; j += 512) {
        unsigned v = raw[j];
        int posn = atomicAdd(&cur[v & 63], 1);
        srt[posn] = v;
    }
    __syncthreads();
    for (int i = tid; i < M; i += 512) ssc[i] = scores[srt[i] >> 6];   // attn
    __syncthreads();
    int wave = tid >> 6, lane = tid & 63;
    for (int n = wave; n < BKT_G; n += 8) {
        int node = b * BKT_G + n;
        if (node >= N) continue;
        int a0 = sstart[n], len = sstart[n + 1] - a0;
        if (len == 0) { bwd[(size_t)node * HID + lane] = 0.f; continue; }
        float acc = -FLT_MAX;
        int k = 0;
        for (; k + 8 <= len; k += 8) {
            float vv[8];
#pragma unroll
            for (int u8 = 0; u8 < 8; u8++) {
                int i = a0 + k + u8;
                vv[u8] = msg[(size_t)(srt[i] >> 6) * HID + lane] * ssc[i];
            }
#pragma unroll
            for (int u8 = 0; u8 < 8; u8++) acc = fmaxf(acc, vv[u8]);
        }
        for (; k < len; k++) {
            int i = a0 + k;
            acc = fmaxf(acc, msg[(size_t)(srt[i] >> 6) * HID + lane] * ssc[i]);
        }
        bwd[(size_t)node * HID + lane] = acc;
    }
}

// ---------------- K6: pre1 = [fwd,bwd]@W1 + b1, 4-chain ILP, fused BN stats ----------------
__global__ __launch_bounds__(256) void k_mlp1(const float* __restrict__ fwd,
                                              const float* __restrict__ bwd,
                                              const float* __restrict__ W1,
                                              const float* __restrict__ b1,
                                              float* pre1, float* gsum, float* gss, int N) {
    __shared__ float lsum[HID], lss[HID];
    int t = threadIdx.x;
    if (t < HID) { lsum[t] = 0.f; lss[t] = 0.f; }
    __syncthreads();
    int h = t & 63, lr = t >> 6;
    float bh = b1[h];
    float s = 0.f, ssq = 0.f;
    for (int n = blockIdx.x * 4 + lr; n < N; n += gridDim.x * 4) {
        const float* fr = fwd + (size_t)n * HID;
        const float* br = bwd + (size_t)n * HID;
        float a0 = bh, a1 = 0.f, a2 = 0.f, a3 = 0.f;   // 4 independent chains
#pragma unroll
        for (int k = 0; k < HID; k += 4) {
            a0 += fr[k]     * W1[k * HID + h];
            a1 += fr[k + 1] * W1[(k + 1) * HID + h];
            a2 += fr[k + 2] * W1[(k + 2) * HID + h];
            a3 += fr[k + 3] * W1[(k + 3) * HID + h];
        }
#pragma unroll
        for (int k = 0; k < HID; k += 4) {
            a0 += br[k]     * W1[(HID + k) * HID + h];
            a1 += br[k + 1] * W1[(HID + k + 1) * HID + h];
            a2 += br[k + 2] * W1[(HID + k + 2) * HID + h];
            a3 += br[k + 3] * W1[(HID + k + 3) * HID + h];
        }
        float acc = (a0 + a1) + (a2 + a3);
        pre1[(size_t)n * HID + h] = acc;
        s += acc; ssq += acc * acc;
    }
    atomicAdd(&lsum[h], s);
    atomicAdd(&lss[h], ssq);
    __syncthreads();
    if (t < HID) { atomicAdd(&gsum[t], lsum[t]); atomicAdd(&gss[t], lss[t]); }
}

// ---------------- K7: pre2 = relu(bn1(pre1))@W2 + b2; bnfin1 folded; 4-chain ILP ----------------
__global__ __launch_bounds__(256) void k_mlp2(const float* __restrict__ pre1,
                                              const float* __restrict__ gsum1,
                                              const float* __restrict__ gss1,
                                              const float* __restrict__ g1,
                                              const float* __restrict__ bb1,
                                              const float* __restrict__ W2,
                                              const float* __restrict__ b2v,
                                              float* pre2, float* gsum, float* gss, int N) {
    __shared__ float lsum[HID], lss[HID];
    __shared__ float sc1[HID], sh1[HID];
    int t = threadIdx.x;
    if (t < HID) {
        lsum[t] = 0.f; lss[t] = 0.f;
        float invN = 1.0f / (float)N;
        float mu = gsum1[t] * invN;
        float var = gss1[t] * invN - mu * mu;
        float rs = rsqrtf(var + 1e-5f);
        float s1 = rs * g1[t];
        sc1[t] = s1;
        sh1[t] = bb1[t] - mu * s1;
    }
    __syncthreads();
    int h = t & 63, lr = t >> 6;
    float bh = b2v[h];
    float s = 0.f, ssq = 0.f;
    for (int n = blockIdx.x * 4 + lr; n < N; n += gridDim.x * 4) {
        const float* pr = pre1 + (size_t)n * HID;
        float a0 = bh, a1 = 0.f, a2 = 0.f, a3 = 0.f;
#pragma unroll
        for (int k = 0; k < HID; k += 4) {
            float z0 = pr[k]     * sc1[k]     + sh1[k];     z0 = (z0 > 0.f) ? z0 : 0.f;
            float z1 = pr[k + 1] * sc1[k + 1] + sh1[k + 1]; z1 = (z1 > 0.f) ? z1 : 0.f;
            float z2 = pr[k + 2] * sc1[k + 2] + sh1[k + 2]; z2 = (z2 > 0.f) ? z2 : 0.f;
            float z3 = pr[k + 3] * sc1[k + 3] + sh1[k + 3]; z3 = (z3 > 0.f) ? z3 : 0.f;
            a0 += z0 * W2[k * HID + h];
            a1 += z1 * W2[(k + 1) * HID + h];
            a2 += z2 * W2[(k + 2) * HID + h];
            a3 += z3 * W2[(k + 3) * HID + h];
        }
        float acc = (a0 + a1) + (a2 + a3);
        pre2[(size_t)n * HID + h] = acc;
        s += acc; ssq += acc * acc;
    }
    atomicAdd(&lsum[h], s);
    atomicAdd(&lss[h], ssq);
    __syncthreads();
    if (t < HID) { atomicAdd(&gsum[t], lsum[t]); atomicAdd(&gss[t], lss[t]); }
}

// ---------------- K8: bnfin2 folded; h2 = relu(bn2(pre2)); gate; f32 out ----------------
__global__ __launch_bounds__(256) void k_out(const float* __restrict__ pre2,
                                             const float* __restrict__ gsum2,
                                             const float* __restrict__ gss2,
                                             const float* __restrict__ g2,
                                             const float* __restrict__ bb2,
                                             const float* __restrict__ amw,
                                             const float* __restrict__ amb,
                                             float* out, int N) {
    __shared__ float sc2[HID], sh2[HID];
    int t = threadIdx.x;
    if (t < HID) {
        float invN = 1.0f / (float)N;
        float mu = gsum2[t] * invN;
        float var = gss2[t] * invN - mu * mu;
        float rs = rsqrtf(var + 1e-5f);
        float s2 = rs * g2[t];
        sc2[t] = s2;
        sh2[t] = bb2[t] - mu * s2;
    }
    __syncthreads();
    int gid = blockIdx.x * blockDim.x + t;
    int n = gid >> 6, h = gid & 63;
    if (n >= N) return;
    float z = pre2[(size_t)n * HID + h] * sc2[h] + sh2[h];
    float h2 = (z > 0.f) ? z : 0.f;
    out[(size_t)n * HID + h] = h2;
    float part = h2 * amw[h];
    for (int m = 32; m >= 1; m >>= 1) part += __shfl_xor(part, m);
    if (h == 0) {
        float gate = 1.0f / (1.0f + expf(-(part + amb[0])));
        out[(size_t)N * HID + n] = gate;
    }
}

extern "C" void kernel_launch(void* const* d_in, const int* in_sizes, int n_in,
                              void* d_out, int out_size, void* d_ws, size_t ws_size,
                              hipStream_t stream) {
    const float* x     = (const float*)d_in[0];
    const int*   ei    = (const int*)d_in[1];
    const float* ea    = (const float*)d_in[2];
    const float* msg   = (const float*)d_in[3];
    const float* Wsrc  = (const float*)d_in[4];
    const float* Wdst  = (const float*)d_in[5];
    const float* Wedge = (const float*)d_in[6];
    const float* avec  = (const float*)d_in[7];
    const float* W1    = (const float*)d_in[8];
    const float* b1    = (const float*)d_in[9];
    const float* g1    = (const float*)d_in[10];
    const float* bb1   = (const float*)d_in[11];
    const float* W2    = (const float*)d_in[12];
    const float* b2    = (const float*)d_in[13];
    const float* g2    = (const float*)d_in[14];
    const float* bb2   = (const float*)d_in[15];
    const float* amw   = (const float*)d_in[16];
    const float* amb   = (const float*)d_in[17];
    float* out = (float*)d_out;

    const int N = in_sizes[0] / IN_DIM;   // 50000
    const int E = in_sizes[1] / 2;        // 800000
    const int NH = N * HID;
    const int nbkt = (N + BKT_G - 1) / BKT_G;   // 782

    // ---- workspace ----
    float* ws = (float*)d_ws;
    float* gsum1  = ws;
    float* gss1   = ws + 64;
    float* gsum2  = ws + 128;
    float* gss2   = ws + 192;
    int*   sflag  = (int*)(ws + 512);
    float* u      = ws + 576;
    float* v      = ws + 704;
    float* w      = ws + 832;   // 16B-aligned
    float* T        = ws + 1024;
    float* p        = T;                               // N
    float* q        = p + N;                           // N
    float* scores   = q + N;                           // E (attn after sortfwd)
    float* rdot     = scores + E;                      // E
    int*   gcur_col = (int*)(rdot + E);                // nbkt
    int*   gcur_row = gcur_col + nbkt;                 // nbkt
    unsigned* bbuf_col = (unsigned*)(gcur_row + nbkt);          // nbkt*BCAP
    unsigned* bbuf_row = bbuf_col + (size_t)nbkt * BCAP;        // nbkt*BCAP
    size_t T_words  = 2 * (size_t)N + 2 * (size_t)E + 2 * (size_t)nbkt
                    + 2 * (size_t)nbkt * BCAP;
    size_t T_sz     = (T_words < (size_t)NH) ? (size_t)NH : T_words;
    float* fwd  = ws + 1024 + T_sz;                    // NH
    float* bwd  = fwd + (size_t)NH;                    // NH
    float* pre1 = T;                                   // overlay transients (dead)
    float* pre2 = fwd;                                 // overlay fwd (dead after mlp1)

    const int pqBlocks   = (N * 64 + 255) / 256;       // 12500
    const int edotBlocks = (E * 8 + 255) / 256;        // 25000

    hipLaunchKernelGGL(k_uvw, dim3(72), dim3(256), 0, stream,
                       Wsrc, Wdst, Wedge, avec, ei, sflag, u, v, w,
                       gcur_col, ws, nbkt);
    hipLaunchKernelGGL(k_pqdot, dim3(pqBlocks + edotBlocks), dim3(256), 0, stream,
                       x, u, v, ea, w, p, q, rdot, N, E, pqBlocks);
    hipLaunchKernelGGL(k_binscore, dim3((E + CHUNK - 1) / CHUNK), dim3(256), 0, stream,
                       ei, sflag, rdot, p, q, scores,
                       gcur_col, gcur_row, bbuf_col, bbuf_row, E, nbkt);
    hipLaunchKernelGGL(k_sortfwd, dim3(nbkt), dim3(512), 0, stream,
                       scores, msg, gcur_col, bbuf_col, fwd, N);
    hipLaunchKernelGGL(k_sortbwd, dim3(nbkt), dim3(512), 0, stream,
                       scores, msg, gcur_row, bbuf_row, bwd, N);
    hipLaunchKernelGGL(k_mlp1, dim3(1024), dim3(256), 0, stream,
                       fwd, bwd, W1, b1, pre1, gsum1, gss1, N);
    hipLaunchKernelGGL(k_mlp2, dim3(1024), dim3(256), 0, stream,
                       pre1, gsum1, gss1, g1, bb1, W2, b2, pre2, gsum2, gss2, N);
    hipLaunchKernelGGL(k_out, dim3(pqBlocks), dim3(256), 0, stream,
                       pre2, gsum2, gss2, g2, bb2, amw, amb, out, N);
}